// Round 5
// baseline (224.860 us; speedup 1.0000x reference)
//
#include <hip/hip_runtime.h>
#include <stdint.h>

// PQ soft-assignment layer, MI355X (gfx950).
// B=65536, feat=512, M=8, K=256, D=64.
// R4: R3 (LDS-resident swizzled codebook, reg-prefetched x, swizzled store
// staging) scaled from 256-thread to 1024-thread blocks. R3 hit 178us
// (~72% of the ~125us HBM floor) at only 8 waves/CU; store bursts don't
// overlap enough to saturate the controller. 16 waves/CU doubles memory
// concurrency: LDS = 64KB codebook + 16x4KB staging = 128KB -> 1 block/CU,
// grid = 256 blocks = exactly one resident round (no tail).

typedef float f32x4 __attribute__((ext_vector_type(4)));
typedef short s16x8 __attribute__((ext_vector_type(8)));
typedef unsigned short u16;

constexpr int MM = 8;     // groups
constexpr int KD = 256;   // codewords per group
constexpr int DD = 64;    // sub-dim
constexpr int NBG = 32;   // b-groups; grid = NBG*8 = 256
constexpr int WAVES = 16; // waves per block

#define LGKM0() asm volatile("s_waitcnt lgkmcnt(0)" ::: "memory")

// float -> bf16 bits, round-to-nearest-even
__device__ __forceinline__ unsigned f2bf1(float f) {
  unsigned u = __float_as_uint(f);
  u += 0x7FFFu + ((u >> 16) & 1u);
  return u >> 16;
}
__device__ __forceinline__ unsigned packbf(float lo, float hi) {
  return f2bf1(lo) | (f2bf1(hi) << 16);
}

// Convert C (f32 [M][K][D]) into bf16 Cm [M][K][D] and CmT [M][D][K] in ws.
__global__ __launch_bounds__(256) void pq_prep(const float* __restrict__ C,
                                               u16* __restrict__ Cm,
                                               u16* __restrict__ Cmt) {
  int idx = blockIdx.x * 256 + threadIdx.x;
  if (idx >= MM * KD * DD) return;
  int d = idx & (DD - 1);
  int k = (idx >> 6) & (KD - 1);
  int m = idx >> 14;
  u16 v = (u16)f2bf1(C[idx]);
  Cm[idx] = v;
  Cmt[(m * DD + d) * KD + k] = v;
}

__global__ __launch_bounds__(1024) void pq_main(const float* __restrict__ x,
                                                const u16* __restrict__ Cm,
                                                const u16* __restrict__ Cmt,
                                                float* __restrict__ xhat,
                                                float* __restrict__ codes,
                                                int niter) {
  // XOR swizzle: element at linear byte L lives at L ^ ((row(L)&7)<<4).
  __shared__ u16 cm_l[KD * DD];        // 32 KB, rows = 128 B (one k's 64 d)
  __shared__ u16 cmt_l[DD * KD];       // 32 KB, rows = 512 B (one d's 256 k)
  __shared__ float stg[WAVES][1024];   // 64 KB, wave-private 16x64f staging
  // total 131072 B -> 1 block/CU, 16 waves/CU

  const int tid = threadIdx.x;
  const int lane = tid & 63;
  const int wave = tid >> 6;   // 0..15
  const int c = lane & 15;
  const int g = lane >> 4;     // 0..3
  const int m = blockIdx.x & 7;
  const int bg = blockIdx.x >> 3;

  // ---------------- cooperative swizzled codebook fill ----------------------
  {
    const char* cs = (const char*)(Cm + (size_t)m * KD * DD);
    const char* ts = (const char*)(Cmt + (size_t)m * DD * KD);
    char* cd = (char*)cm_l;
    char* td = (char*)cmt_l;
#pragma unroll
    for (int i = 0; i < 2; ++i) {
      int byte = (tid + i * 1024) * 16;
      s16x8 v = *(const s16x8*)(cs + byte);
      *(s16x8*)(cd + (byte ^ (((byte >> 7) & 7) << 4))) = v;
      s16x8 w = *(const s16x8*)(ts + byte);
      *(s16x8*)(td + (byte ^ (((byte >> 9) & 7) << 4))) = w;
    }
  }
  __syncthreads();   // only barrier in the kernel

  // Per-lane swizzled base addresses.
  // Within-row offset for frag reads = kf*64 + g*16; XOR splits bitwise:
  // bits4-5: (g*16)^((c&3)<<4); bit6: kf^((c>>2)&1) -> even/odd base pair.
  const int cbit = (c >> 2) & 1;
  const int gsw = (g * 16) ^ ((c & 3) << 4);
  const char* A_e = (const char*)cm_l + c * 128 + gsw + cbit * 64;         // kf=0
  const char* A_o = (const char*)cm_l + c * 128 + gsw + 64 - cbit * 64;    // kf=1
  const char* B_e = (const char*)cmt_l + c * 512 + gsw + cbit * 64;        // even kf: +kf*64
  const char* B_o = (const char*)cmt_l + c * 512 + gsw + 64 - cbit * 64;   // odd kf: +(kf&~1)*64
  char* S_e = (char*)stg[wave] + c * 256 + gsw + cbit * 64;                // even rf: +rf*64
  char* S_o = (char*)stg[wave] + c * 256 + gsw + 64 - cbit * 64;           // odd rf: +(rf&~1)*64
  const char* Sr = (const char*)stg[wave];
  const int rsub = lane >> 4;      // staging read: row-in-quad
  const int slot = lane & 15;      // staging read: 16B slot
  const int xs_e = (slot * 16) ^ (rsub << 4);   // t2 even; t2 odd: ^0x40

  const int rowstep = WAVES * 16;                  // 256 rows per iter
  const int rowblk = bg * niter * rowstep + wave * 16;
  const size_t xstr = MM * DD;     // 512 floats

  f32x4 xv[4];
  {
    const float* xp = x + (size_t)(rowblk + c) * xstr + m * DD + g * 8;
    xv[0] = *(const f32x4*)(xp);
    xv[1] = *(const f32x4*)(xp + 4);
    xv[2] = *(const f32x4*)(xp + 32);
    xv[3] = *(const f32x4*)(xp + 36);
  }

  for (int t = 0; t < niter; ++t) {
    // -------- prefetch next x tile (issued before all compute) --------------
    f32x4 xn[4];
    {
      int tn = t + 1 < niter ? t + 1 : t;
      const float* xp = x + (size_t)(rowblk + tn * rowstep + c) * xstr + m * DD + g * 8;
      xn[0] = *(const f32x4*)(xp);
      xn[1] = *(const f32x4*)(xp + 4);
      xn[2] = *(const f32x4*)(xp + 32);
      xn[3] = *(const f32x4*)(xp + 36);
    }

    // -------- normalize + bf16 B-frags --------------------------------------
    float ssq = 0.f;
#pragma unroll
    for (int i = 0; i < 4; ++i)
      ssq += xv[i].x * xv[i].x + xv[i].y * xv[i].y + xv[i].z * xv[i].z + xv[i].w * xv[i].w;
    ssq += __shfl_xor(ssq, 16);
    ssq += __shfl_xor(ssq, 32);
    const float inv = 1.0f / fmaxf(sqrtf(ssq), 1e-12f);

    s16x8 bx[2];
#pragma unroll
    for (int kf = 0; kf < 2; ++kf) {
      union { s16x8 v; unsigned u[4]; } un;
#pragma unroll
      for (int tt = 0; tt < 2; ++tt) {
        f32x4 q = xv[kf * 2 + tt];
        un.u[tt * 2 + 0] = packbf(q.x * inv, q.y * inv);
        un.u[tt * 2 + 1] = packbf(q.z * inv, q.w * inv);
      }
      bx[kf] = un.v;
    }

    // -------- MFMA1: S^T[k][b] from LDS codebook ----------------------------
    f32x4 acc[16];
#pragma unroll
    for (int rf = 0; rf < 16; ++rf) acc[rf] = (f32x4){0.f, 0.f, 0.f, 0.f};
#pragma unroll
    for (int rf = 0; rf < 16; ++rf) {
      s16x8 a0 = *(const s16x8*)(A_e + rf * 2048);
      acc[rf] = __builtin_amdgcn_mfma_f32_16x16x32_bf16(a0, bx[0], acc[rf], 0, 0, 0);
      s16x8 a1 = *(const s16x8*)(A_o + rf * 2048);
      acc[rf] = __builtin_amdgcn_mfma_f32_16x16x32_bf16(a1, bx[1], acc[rf], 0, 0, 0);
    }

    // -------- softmax (lane-local + 2 shuffles) -----------------------------
    float mx = -3.0e38f;
#pragma unroll
    for (int rf = 0; rf < 16; ++rf)
      mx = fmaxf(mx, fmaxf(fmaxf(acc[rf].x, acc[rf].y), fmaxf(acc[rf].z, acc[rf].w)));
    mx = fmaxf(mx, __shfl_xor(mx, 16));
    mx = fmaxf(mx, __shfl_xor(mx, 32));

    float sum = 0.f;
#pragma unroll
    for (int rf = 0; rf < 16; ++rf) {
      acc[rf].x = __expf(acc[rf].x - mx);
      acc[rf].y = __expf(acc[rf].y - mx);
      acc[rf].z = __expf(acc[rf].z - mx);
      acc[rf].w = __expf(acc[rf].w - mx);
      sum += acc[rf].x + acc[rf].y + acc[rf].z + acc[rf].w;
    }
    sum += __shfl_xor(sum, 16);
    sum += __shfl_xor(sum, 32);
    const float rs = 1.0f / sum;
#pragma unroll
    for (int rf = 0; rf < 16; ++rf) {
      acc[rf].x *= rs; acc[rf].y *= rs; acc[rf].z *= rs; acc[rf].w *= rs;
    }

    // -------- store codes via swizzled staging (4 quarters of 64 k) ---------
#pragma unroll
    for (int q = 0; q < 4; ++q) {
      LGKM0();  // WAR vs previous quarter's reads
#pragma unroll
      for (int rf = 0; rf < 4; ++rf) {
        char* p = (rf & 1) ? (S_o + (rf & ~1) * 64) : (S_e + rf * 64);
        *(f32x4*)p = acc[q * 4 + rf];
      }
      LGKM0();
#pragma unroll
      for (int t2 = 0; t2 < 4; ++t2) {
        int r = 4 * t2 + rsub;
        f32x4 v = *(const f32x4*)(Sr + r * 256 + ((t2 & 1) ? (xs_e ^ 0x40) : xs_e));
        int grow = rowblk + t * rowstep + r;
        *(f32x4*)(codes + ((size_t)grow * MM + m) * KD + q * 64 + slot * 4) = v;
      }
    }

    // -------- build P^T B-frags via register shuffles -----------------------
    unsigned w0[16], w1[16];
#pragma unroll
    for (int rf = 0; rf < 16; ++rf) {
      w0[rf] = packbf(acc[rf].x, acc[rf].y);
      w1[rf] = packbf(acc[rf].z, acc[rf].w);
    }
    const int laneA = c + 32 * (g & 1);
    const int laneB = laneA + 16;
    const bool hi = (g >> 1) != 0;
    s16x8 Bp[8];
#pragma unroll
    for (int kf = 0; kf < 8; ++kf) {
      unsigned a0e = __shfl(w0[2 * kf], laneA);
      unsigned a1e = __shfl(w1[2 * kf], laneA);
      unsigned a0o = __shfl(w0[2 * kf + 1], laneA);
      unsigned a1o = __shfl(w1[2 * kf + 1], laneA);
      unsigned b0e = __shfl(w0[2 * kf], laneB);
      unsigned b1e = __shfl(w1[2 * kf], laneB);
      unsigned b0o = __shfl(w0[2 * kf + 1], laneB);
      unsigned b1o = __shfl(w1[2 * kf + 1], laneB);
      union { s16x8 v; unsigned u[4]; } un;
      un.u[0] = hi ? a0o : a0e;
      un.u[1] = hi ? a1o : a1e;
      un.u[2] = hi ? b0o : b0e;
      un.u[3] = hi ? b1o : b1e;
      Bp[kf] = un.v;
    }

    // -------- MFMA2: xhat^T[d][b] from LDS codebook -------------------------
    f32x4 acc2[4];
#pragma unroll
    for (int rf2 = 0; rf2 < 4; ++rf2) acc2[rf2] = (f32x4){0.f, 0.f, 0.f, 0.f};
#pragma unroll
    for (int rf2 = 0; rf2 < 4; ++rf2) {
#pragma unroll
      for (int kf = 0; kf < 8; ++kf) {
        const char* p = (kf & 1) ? (B_o + (kf & ~1) * 64) : (B_e + kf * 64);
        s16x8 A = *(const s16x8*)(p + rf2 * 8192);
        acc2[rf2] = __builtin_amdgcn_mfma_f32_16x16x32_bf16(A, Bp[kf], acc2[rf2], 0, 0, 0);
      }
    }

    // -------- store x_hat via swizzled staging ------------------------------
    LGKM0();  // WAR vs codes reads
#pragma unroll
    for (int rf2 = 0; rf2 < 4; ++rf2) {
      char* p = (rf2 & 1) ? (S_o + (rf2 & ~1) * 64) : (S_e + rf2 * 64);
      *(f32x4*)p = acc2[rf2];
    }
    LGKM0();
#pragma unroll
    for (int t2 = 0; t2 < 4; ++t2) {
      int r = 4 * t2 + rsub;
      f32x4 v = *(const f32x4*)(Sr + r * 256 + ((t2 & 1) ? (xs_e ^ 0x40) : xs_e));
      int grow = rowblk + t * rowstep + r;
      *(f32x4*)(xhat + (size_t)grow * xstr + m * DD + slot * 4) = v;
    }

    xv[0] = xn[0]; xv[1] = xn[1]; xv[2] = xn[2]; xv[3] = xn[3];
  }
}

extern "C" void kernel_launch(void* const* d_in, const int* in_sizes, int n_in,
                              void* d_out, int out_size, void* d_ws, size_t ws_size,
                              hipStream_t stream) {
  const float* x = (const float*)d_in[0];
  const float* C = (const float*)d_in[1];
  const int B = in_sizes[0] / (MM * DD);   // 65536

  float* xhat = (float*)d_out;
  float* codes = (float*)d_out + (size_t)B * MM * DD;

  u16* Cm = (u16*)d_ws;
  u16* Cmt = Cm + MM * KD * DD;   // 512 KB total in ws

  const int niter = B / (NBG * WAVES * 16);        // 8

  pq_prep<<<(MM * KD * DD + 255) / 256, 256, 0, stream>>>(C, Cm, Cmt);
  pq_main<<<NBG * MM, 1024, 0, stream>>>(x, Cm, Cmt, xhat, codes, niter);
}

// Round 6
// 182.545 us; speedup vs baseline: 1.2318x; 1.2318x over previous
//
#include <hip/hip_runtime.h>
#include <stdint.h>

// PQ soft-assignment layer, MI355X (gfx950).
// B=65536, feat=512, M=8, K=256, D=64.
// R5: clean concurrency test. R3 (178us) = 256-thr blocks, 2 blocks/CU,
// 8 waves/CU. R4 (225us) changed waves AND residency (1-block/CU exact-fit
// grid -> imbalance). R5 keeps R3's residency/grid/work-split EXACTLY
// (grid 1024, 2 blocks/CU, 80KB LDS, 512 rows/block, 2 residency rounds)
// and only fattens blocks to 512 threads (8 waves) -> 16 waves/CU.
// Staging shrunk to 2KB/wave (codes in eighths, xhat in halves) to hold
// LDS at 32+32+16 = 80KB.

typedef float f32x4 __attribute__((ext_vector_type(4)));
typedef short s16x8 __attribute__((ext_vector_type(8)));
typedef unsigned short u16;

constexpr int MM = 8;     // groups
constexpr int KD = 256;   // codewords per group
constexpr int DD = 64;    // sub-dim
constexpr int NBG = 128;  // b-groups; grid = NBG*8 = 1024
constexpr int WAVES = 8;  // waves per block (512 threads)

#define LGKM0() asm volatile("s_waitcnt lgkmcnt(0)" ::: "memory")

// float -> bf16 bits, round-to-nearest-even
__device__ __forceinline__ unsigned f2bf1(float f) {
  unsigned u = __float_as_uint(f);
  u += 0x7FFFu + ((u >> 16) & 1u);
  return u >> 16;
}
__device__ __forceinline__ unsigned packbf(float lo, float hi) {
  return f2bf1(lo) | (f2bf1(hi) << 16);
}

// Convert C (f32 [M][K][D]) into bf16 Cm [M][K][D] and CmT [M][D][K] in ws.
__global__ __launch_bounds__(256) void pq_prep(const float* __restrict__ C,
                                               u16* __restrict__ Cm,
                                               u16* __restrict__ Cmt) {
  int idx = blockIdx.x * 256 + threadIdx.x;
  if (idx >= MM * KD * DD) return;
  int d = idx & (DD - 1);
  int k = (idx >> 6) & (KD - 1);
  int m = idx >> 14;
  u16 v = (u16)f2bf1(C[idx]);
  Cm[idx] = v;
  Cmt[(m * DD + d) * KD + k] = v;
}

__global__ __launch_bounds__(512) void pq_main(const float* __restrict__ x,
                                               const u16* __restrict__ Cm,
                                               const u16* __restrict__ Cmt,
                                               float* __restrict__ xhat,
                                               float* __restrict__ codes,
                                               int niter) {
  // XOR swizzle: element at linear byte L lives at L ^ ((row(L)&7)<<4).
  __shared__ u16 cm_l[KD * DD];        // 32 KB, rows = 128 B (one k's 64 d)
  __shared__ u16 cmt_l[DD * KD];       // 32 KB, rows = 512 B (one d's 256 k)
  __shared__ float stg[WAVES][512];    // 16 KB, wave-private 16x32f staging
  // total 81920 B -> 2 blocks/CU, 16 waves/CU

  const int tid = threadIdx.x;
  const int lane = tid & 63;
  const int wave = tid >> 6;   // 0..7
  const int c = lane & 15;
  const int g = lane >> 4;     // 0..3
  const int m = blockIdx.x & 7;
  const int bg = blockIdx.x >> 3;

  // ---------------- cooperative swizzled codebook fill ----------------------
  {
    const char* cs = (const char*)(Cm + (size_t)m * KD * DD);
    const char* ts = (const char*)(Cmt + (size_t)m * DD * KD);
    char* cd = (char*)cm_l;
    char* td = (char*)cmt_l;
#pragma unroll
    for (int i = 0; i < 4; ++i) {
      int byte = (tid + i * 512) * 16;
      s16x8 v = *(const s16x8*)(cs + byte);
      *(s16x8*)(cd + (byte ^ (((byte >> 7) & 7) << 4))) = v;
      s16x8 w = *(const s16x8*)(ts + byte);
      *(s16x8*)(td + (byte ^ (((byte >> 9) & 7) << 4))) = w;
    }
  }
  __syncthreads();   // only barrier in the kernel

  // Per-lane swizzled base addresses for the codebook (as R3/R4).
  const int cbit = (c >> 2) & 1;
  const int gsw = (g * 16) ^ ((c & 3) << 4);
  const char* A_e = (const char*)cm_l + c * 128 + gsw + cbit * 64;         // kf=0
  const char* A_o = (const char*)cm_l + c * 128 + gsw + 64 - cbit * 64;    // kf=1
  const char* B_e = (const char*)cmt_l + c * 512 + gsw + cbit * 64;        // even kf
  const char* B_o = (const char*)cmt_l + c * 512 + gsw + 64 - cbit * 64;   // odd kf

  // Staging (16 rows x 128 B, swizzle byte ^= (row&7)<<4).
  // Write side: lane(c,g) writes row c, k_local {4g, 16+4g} -> bytes {16g, 64+16g}.
  char* Sw0 = (char*)stg[wave] + c * 128 + ((16 * g) ^ ((c & 7) << 4));
  char* Sw1 = Sw0 + (((c >> 2) & 1) ? -64 : 64);   // = Sw0 ^ 64
  // Read side: pass p covers rows p*8 + (lane>>3), 16B slot = lane&7.
  const int rrow = lane >> 3;    // 0..7
  const int slot = lane & 7;     // 0..7
  const char* Srd = (const char*)stg[wave] + rrow * 128 + ((slot * 16) ^ (rrow << 4));

  const int rowstep = WAVES * 16;                  // 128 rows per iter
  const int rowblk = bg * niter * rowstep + wave * 16;
  const size_t xstr = MM * DD;     // 512 floats

  f32x4 xv[4];
  {
    const float* xp = x + (size_t)(rowblk + c) * xstr + m * DD + g * 8;
    xv[0] = *(const f32x4*)(xp);
    xv[1] = *(const f32x4*)(xp + 4);
    xv[2] = *(const f32x4*)(xp + 32);
    xv[3] = *(const f32x4*)(xp + 36);
  }

  for (int t = 0; t < niter; ++t) {
    // -------- prefetch next x tile (issued before all compute) --------------
    f32x4 xn[4];
    {
      int tn = t + 1 < niter ? t + 1 : t;
      const float* xp = x + (size_t)(rowblk + tn * rowstep + c) * xstr + m * DD + g * 8;
      xn[0] = *(const f32x4*)(xp);
      xn[1] = *(const f32x4*)(xp + 4);
      xn[2] = *(const f32x4*)(xp + 32);
      xn[3] = *(const f32x4*)(xp + 36);
    }

    // -------- normalize + bf16 B-frags --------------------------------------
    float ssq = 0.f;
#pragma unroll
    for (int i = 0; i < 4; ++i)
      ssq += xv[i].x * xv[i].x + xv[i].y * xv[i].y + xv[i].z * xv[i].z + xv[i].w * xv[i].w;
    ssq += __shfl_xor(ssq, 16);
    ssq += __shfl_xor(ssq, 32);
    const float inv = 1.0f / fmaxf(sqrtf(ssq), 1e-12f);

    s16x8 bx[2];
#pragma unroll
    for (int kf = 0; kf < 2; ++kf) {
      union { s16x8 v; unsigned u[4]; } un;
#pragma unroll
      for (int tt = 0; tt < 2; ++tt) {
        f32x4 q = xv[kf * 2 + tt];
        un.u[tt * 2 + 0] = packbf(q.x * inv, q.y * inv);
        un.u[tt * 2 + 1] = packbf(q.z * inv, q.w * inv);
      }
      bx[kf] = un.v;
    }

    // -------- MFMA1: S^T[k][b] from LDS codebook ----------------------------
    f32x4 acc[16];
#pragma unroll
    for (int rf = 0; rf < 16; ++rf) acc[rf] = (f32x4){0.f, 0.f, 0.f, 0.f};
#pragma unroll
    for (int rf = 0; rf < 16; ++rf) {
      s16x8 a0 = *(const s16x8*)(A_e + rf * 2048);
      acc[rf] = __builtin_amdgcn_mfma_f32_16x16x32_bf16(a0, bx[0], acc[rf], 0, 0, 0);
      s16x8 a1 = *(const s16x8*)(A_o + rf * 2048);
      acc[rf] = __builtin_amdgcn_mfma_f32_16x16x32_bf16(a1, bx[1], acc[rf], 0, 0, 0);
    }

    // -------- softmax (lane-local + 2 shuffles) -----------------------------
    float mx = -3.0e38f;
#pragma unroll
    for (int rf = 0; rf < 16; ++rf)
      mx = fmaxf(mx, fmaxf(fmaxf(acc[rf].x, acc[rf].y), fmaxf(acc[rf].z, acc[rf].w)));
    mx = fmaxf(mx, __shfl_xor(mx, 16));
    mx = fmaxf(mx, __shfl_xor(mx, 32));

    float sum = 0.f;
#pragma unroll
    for (int rf = 0; rf < 16; ++rf) {
      acc[rf].x = __expf(acc[rf].x - mx);
      acc[rf].y = __expf(acc[rf].y - mx);
      acc[rf].z = __expf(acc[rf].z - mx);
      acc[rf].w = __expf(acc[rf].w - mx);
      sum += acc[rf].x + acc[rf].y + acc[rf].z + acc[rf].w;
    }
    sum += __shfl_xor(sum, 16);
    sum += __shfl_xor(sum, 32);
    const float rs = 1.0f / sum;
#pragma unroll
    for (int rf = 0; rf < 16; ++rf) {
      acc[rf].x *= rs; acc[rf].y *= rs; acc[rf].z *= rs; acc[rf].w *= rs;
    }

    // -------- store codes via swizzled staging (8 eighths of 32 k) ----------
#pragma unroll
    for (int e = 0; e < 8; ++e) {
      LGKM0();  // WAR guard vs previous eighth's reads (cheap: lgkm ~0 here)
      *(f32x4*)Sw0 = acc[2 * e];
      *(f32x4*)Sw1 = acc[2 * e + 1];
      LGKM0();  // RAW: writes visible before reads
#pragma unroll
      for (int p = 0; p < 2; ++p) {
        f32x4 v = *(const f32x4*)(Srd + p * 1024);
        int grow = rowblk + t * rowstep + p * 8 + rrow;
        *(f32x4*)(codes + ((size_t)grow * MM + m) * KD + e * 32 + slot * 4) = v;
      }
    }

    // -------- build P^T B-frags via register shuffles -----------------------
    unsigned w0[16], w1[16];
#pragma unroll
    for (int rf = 0; rf < 16; ++rf) {
      w0[rf] = packbf(acc[rf].x, acc[rf].y);
      w1[rf] = packbf(acc[rf].z, acc[rf].w);
    }
    const int laneA = c + 32 * (g & 1);
    const int laneB = laneA + 16;
    const bool hi = (g >> 1) != 0;
    s16x8 Bp[8];
#pragma unroll
    for (int kf = 0; kf < 8; ++kf) {
      unsigned a0e = __shfl(w0[2 * kf], laneA);
      unsigned a1e = __shfl(w1[2 * kf], laneA);
      unsigned a0o = __shfl(w0[2 * kf + 1], laneA);
      unsigned a1o = __shfl(w1[2 * kf + 1], laneA);
      unsigned b0e = __shfl(w0[2 * kf], laneB);
      unsigned b1e = __shfl(w1[2 * kf], laneB);
      unsigned b0o = __shfl(w0[2 * kf + 1], laneB);
      unsigned b1o = __shfl(w1[2 * kf + 1], laneB);
      union { s16x8 v; unsigned u[4]; } un;
      un.u[0] = hi ? a0o : a0e;
      un.u[1] = hi ? a1o : a1e;
      un.u[2] = hi ? b0o : b0e;
      un.u[3] = hi ? b1o : b1e;
      Bp[kf] = un.v;
    }

    // -------- MFMA2: xhat^T[d][b] from LDS codebook -------------------------
    f32x4 acc2[4];
#pragma unroll
    for (int rf2 = 0; rf2 < 4; ++rf2) acc2[rf2] = (f32x4){0.f, 0.f, 0.f, 0.f};
#pragma unroll
    for (int rf2 = 0; rf2 < 4; ++rf2) {
#pragma unroll
      for (int kf = 0; kf < 8; ++kf) {
        const char* p = (kf & 1) ? (B_o + (kf & ~1) * 64) : (B_e + kf * 64);
        s16x8 A = *(const s16x8*)(p + rf2 * 8192);
        acc2[rf2] = __builtin_amdgcn_mfma_f32_16x16x32_bf16(A, Bp[kf], acc2[rf2], 0, 0, 0);
      }
    }

    // -------- store x_hat via swizzled staging (2 halves of 32 d) -----------
#pragma unroll
    for (int h = 0; h < 2; ++h) {
      LGKM0();  // WAR guard
      *(f32x4*)Sw0 = acc2[2 * h];
      *(f32x4*)Sw1 = acc2[2 * h + 1];
      LGKM0();  // RAW
#pragma unroll
      for (int p = 0; p < 2; ++p) {
        f32x4 v = *(const f32x4*)(Srd + p * 1024);
        int grow = rowblk + t * rowstep + p * 8 + rrow;
        *(f32x4*)(xhat + (size_t)grow * xstr + m * DD + h * 32 + slot * 4) = v;
      }
    }

    xv[0] = xn[0]; xv[1] = xn[1]; xv[2] = xn[2]; xv[3] = xn[3];
  }
}

extern "C" void kernel_launch(void* const* d_in, const int* in_sizes, int n_in,
                              void* d_out, int out_size, void* d_ws, size_t ws_size,
                              hipStream_t stream) {
  const float* x = (const float*)d_in[0];
  const float* C = (const float*)d_in[1];
  const int B = in_sizes[0] / (MM * DD);   // 65536

  float* xhat = (float*)d_out;
  float* codes = (float*)d_out + (size_t)B * MM * DD;

  u16* Cm = (u16*)d_ws;
  u16* Cmt = Cm + MM * KD * DD;   // 512 KB total in ws

  const int niter = B / (NBG * WAVES * 16);        // 4

  pq_prep<<<(MM * KD * DD + 255) / 256, 256, 0, stream>>>(C, Cm, Cmt);
  pq_main<<<NBG * MM, WAVES * 64, 0, stream>>>(x, Cm, Cmt, xhat, codes, niter);
}

// Round 8
// 143.209 us; speedup vs baseline: 1.5702x; 1.2747x over previous
//
#include <hip/hip_runtime.h>
#include <stdint.h>

// PQ soft-assignment layer, MI355X (gfx950).
// B=65536, feat=512, M=8, K=256, D=64.
// R7 = R6 resubmitted verbatim (R7's bench died with UnresponsiveContainer —
// infra failure, no data).
// R6 = R5 (LDS codebook, 512-thr blocks, 16 waves/CU, swizzled staging) +
//  (a) softmax WITHOUT max-subtraction: |logit| <= 1 after L2-norm, so
//      exp() is in [0.37, 2.72] -- shift is unnecessary. Removes 48 fmax,
//      2 shuffles, and the max->exp serial dependency.
//  (b) non-temporal output stores (outputs are never re-read).
// History: 805 (R0 latency-bound) -> 178 (R3 LDS codebook) -> flat under
// waves/CU 8->16 (R5) => BW-bound on ~15/85 mixed stream at ~4.9 TB/s.

typedef float f32x4 __attribute__((ext_vector_type(4)));
typedef short s16x8 __attribute__((ext_vector_type(8)));
typedef unsigned short u16;

constexpr int MM = 8;     // groups
constexpr int KD = 256;   // codewords per group
constexpr int DD = 64;    // sub-dim
constexpr int NBG = 128;  // b-groups; grid = NBG*8 = 1024
constexpr int WAVES = 8;  // waves per block (512 threads)

#define LGKM0() asm volatile("s_waitcnt lgkmcnt(0)" ::: "memory")

// float -> bf16 bits, round-to-nearest-even
__device__ __forceinline__ unsigned f2bf1(float f) {
  unsigned u = __float_as_uint(f);
  u += 0x7FFFu + ((u >> 16) & 1u);
  return u >> 16;
}
__device__ __forceinline__ unsigned packbf(float lo, float hi) {
  return f2bf1(lo) | (f2bf1(hi) << 16);
}

// Convert C (f32 [M][K][D]) into bf16 Cm [M][K][D] and CmT [M][D][K] in ws.
__global__ __launch_bounds__(256) void pq_prep(const float* __restrict__ C,
                                               u16* __restrict__ Cm,
                                               u16* __restrict__ Cmt) {
  int idx = blockIdx.x * 256 + threadIdx.x;
  if (idx >= MM * KD * DD) return;
  int d = idx & (DD - 1);
  int k = (idx >> 6) & (KD - 1);
  int m = idx >> 14;
  u16 v = (u16)f2bf1(C[idx]);
  Cm[idx] = v;
  Cmt[(m * DD + d) * KD + k] = v;
}

__global__ __launch_bounds__(512) void pq_main(const float* __restrict__ x,
                                               const u16* __restrict__ Cm,
                                               const u16* __restrict__ Cmt,
                                               float* __restrict__ xhat,
                                               float* __restrict__ codes,
                                               int niter) {
  // XOR swizzle: element at linear byte L lives at L ^ ((row(L)&7)<<4).
  __shared__ u16 cm_l[KD * DD];        // 32 KB, rows = 128 B (one k's 64 d)
  __shared__ u16 cmt_l[DD * KD];       // 32 KB, rows = 512 B (one d's 256 k)
  __shared__ float stg[WAVES][512];    // 16 KB, wave-private 16x32f staging
  // total 81920 B -> 2 blocks/CU, 16 waves/CU

  const int tid = threadIdx.x;
  const int lane = tid & 63;
  const int wave = tid >> 6;   // 0..7
  const int c = lane & 15;
  const int g = lane >> 4;     // 0..3
  const int m = blockIdx.x & 7;
  const int bg = blockIdx.x >> 3;

  // ---------------- cooperative swizzled codebook fill ----------------------
  {
    const char* cs = (const char*)(Cm + (size_t)m * KD * DD);
    const char* ts = (const char*)(Cmt + (size_t)m * DD * KD);
    char* cd = (char*)cm_l;
    char* td = (char*)cmt_l;
#pragma unroll
    for (int i = 0; i < 4; ++i) {
      int byte = (tid + i * 512) * 16;
      s16x8 v = *(const s16x8*)(cs + byte);
      *(s16x8*)(cd + (byte ^ (((byte >> 7) & 7) << 4))) = v;
      s16x8 w = *(const s16x8*)(ts + byte);
      *(s16x8*)(td + (byte ^ (((byte >> 9) & 7) << 4))) = w;
    }
  }
  __syncthreads();   // only barrier in the kernel

  // Per-lane swizzled base addresses for the codebook (as R3/R4).
  const int cbit = (c >> 2) & 1;
  const int gsw = (g * 16) ^ ((c & 3) << 4);
  const char* A_e = (const char*)cm_l + c * 128 + gsw + cbit * 64;         // kf=0
  const char* A_o = (const char*)cm_l + c * 128 + gsw + 64 - cbit * 64;    // kf=1
  const char* B_e = (const char*)cmt_l + c * 512 + gsw + cbit * 64;        // even kf
  const char* B_o = (const char*)cmt_l + c * 512 + gsw + 64 - cbit * 64;   // odd kf

  // Staging (16 rows x 128 B, swizzle byte ^= (row&7)<<4).
  // Write side: lane(c,g) writes row c, k_local {4g, 16+4g} -> bytes {16g, 64+16g}.
  char* Sw0 = (char*)stg[wave] + c * 128 + ((16 * g) ^ ((c & 7) << 4));
  char* Sw1 = Sw0 + (((c >> 2) & 1) ? -64 : 64);   // = Sw0 ^ 64
  // Read side: pass p covers rows p*8 + (lane>>3), 16B slot = lane&7.
  const int rrow = lane >> 3;    // 0..7
  const int slot = lane & 7;     // 0..7
  const char* Srd = (const char*)stg[wave] + rrow * 128 + ((slot * 16) ^ (rrow << 4));

  const int rowstep = WAVES * 16;                  // 128 rows per iter
  const int rowblk = bg * niter * rowstep + wave * 16;
  const size_t xstr = MM * DD;     // 512 floats

  f32x4 xv[4];
  {
    const float* xp = x + (size_t)(rowblk + c) * xstr + m * DD + g * 8;
    xv[0] = *(const f32x4*)(xp);
    xv[1] = *(const f32x4*)(xp + 4);
    xv[2] = *(const f32x4*)(xp + 32);
    xv[3] = *(const f32x4*)(xp + 36);
  }

  for (int t = 0; t < niter; ++t) {
    // -------- prefetch next x tile (issued before all compute) --------------
    f32x4 xn[4];
    {
      int tn = t + 1 < niter ? t + 1 : t;
      const float* xp = x + (size_t)(rowblk + tn * rowstep + c) * xstr + m * DD + g * 8;
      xn[0] = *(const f32x4*)(xp);
      xn[1] = *(const f32x4*)(xp + 4);
      xn[2] = *(const f32x4*)(xp + 32);
      xn[3] = *(const f32x4*)(xp + 36);
    }

    // -------- normalize + bf16 B-frags --------------------------------------
    float ssq = 0.f;
#pragma unroll
    for (int i = 0; i < 4; ++i)
      ssq += xv[i].x * xv[i].x + xv[i].y * xv[i].y + xv[i].z * xv[i].z + xv[i].w * xv[i].w;
    ssq += __shfl_xor(ssq, 16);
    ssq += __shfl_xor(ssq, 32);
    const float inv = 1.0f / fmaxf(sqrtf(ssq), 1e-12f);

    s16x8 bx[2];
#pragma unroll
    for (int kf = 0; kf < 2; ++kf) {
      union { s16x8 v; unsigned u[4]; } un;
#pragma unroll
      for (int tt = 0; tt < 2; ++tt) {
        f32x4 q = xv[kf * 2 + tt];
        un.u[tt * 2 + 0] = packbf(q.x * inv, q.y * inv);
        un.u[tt * 2 + 1] = packbf(q.z * inv, q.w * inv);
      }
      bx[kf] = un.v;
    }

    // -------- MFMA1: S^T[k][b] from LDS codebook ----------------------------
    f32x4 acc[16];
#pragma unroll
    for (int rf = 0; rf < 16; ++rf) acc[rf] = (f32x4){0.f, 0.f, 0.f, 0.f};
#pragma unroll
    for (int rf = 0; rf < 16; ++rf) {
      s16x8 a0 = *(const s16x8*)(A_e + rf * 2048);
      acc[rf] = __builtin_amdgcn_mfma_f32_16x16x32_bf16(a0, bx[0], acc[rf], 0, 0, 0);
      s16x8 a1 = *(const s16x8*)(A_o + rf * 2048);
      acc[rf] = __builtin_amdgcn_mfma_f32_16x16x32_bf16(a1, bx[1], acc[rf], 0, 0, 0);
    }

    // -------- softmax WITHOUT max-shift: |logit| <= 1 -----------------------
    float sum = 0.f;
#pragma unroll
    for (int rf = 0; rf < 16; ++rf) {
      acc[rf].x = __expf(acc[rf].x);
      acc[rf].y = __expf(acc[rf].y);
      acc[rf].z = __expf(acc[rf].z);
      acc[rf].w = __expf(acc[rf].w);
      sum += acc[rf].x + acc[rf].y + acc[rf].z + acc[rf].w;
    }
    sum += __shfl_xor(sum, 16);
    sum += __shfl_xor(sum, 32);
    const float rs = 1.0f / sum;
#pragma unroll
    for (int rf = 0; rf < 16; ++rf) {
      acc[rf].x *= rs; acc[rf].y *= rs; acc[rf].z *= rs; acc[rf].w *= rs;
    }

    // -------- store codes via swizzled staging (8 eighths of 32 k) ----------
#pragma unroll
    for (int e = 0; e < 8; ++e) {
      LGKM0();  // WAR guard vs previous eighth's reads
      *(f32x4*)Sw0 = acc[2 * e];
      *(f32x4*)Sw1 = acc[2 * e + 1];
      LGKM0();  // RAW: writes visible before reads
#pragma unroll
      for (int p = 0; p < 2; ++p) {
        f32x4 v = *(const f32x4*)(Srd + p * 1024);
        int grow = rowblk + t * rowstep + p * 8 + rrow;
        __builtin_nontemporal_store(
            v, (f32x4*)(codes + ((size_t)grow * MM + m) * KD + e * 32 + slot * 4));
      }
    }

    // -------- build P^T B-frags via register shuffles -----------------------
    unsigned w0[16], w1[16];
#pragma unroll
    for (int rf = 0; rf < 16; ++rf) {
      w0[rf] = packbf(acc[rf].x, acc[rf].y);
      w1[rf] = packbf(acc[rf].z, acc[rf].w);
    }
    const int laneA = c + 32 * (g & 1);
    const int laneB = laneA + 16;
    const bool hi = (g >> 1) != 0;
    s16x8 Bp[8];
#pragma unroll
    for (int kf = 0; kf < 8; ++kf) {
      unsigned a0e = __shfl(w0[2 * kf], laneA);
      unsigned a1e = __shfl(w1[2 * kf], laneA);
      unsigned a0o = __shfl(w0[2 * kf + 1], laneA);
      unsigned a1o = __shfl(w1[2 * kf + 1], laneA);
      unsigned b0e = __shfl(w0[2 * kf], laneB);
      unsigned b1e = __shfl(w1[2 * kf], laneB);
      unsigned b0o = __shfl(w0[2 * kf + 1], laneB);
      unsigned b1o = __shfl(w1[2 * kf + 1], laneB);
      union { s16x8 v; unsigned u[4]; } un;
      un.u[0] = hi ? a0o : a0e;
      un.u[1] = hi ? a1o : a1e;
      un.u[2] = hi ? b0o : b0e;
      un.u[3] = hi ? b1o : b1e;
      Bp[kf] = un.v;
    }

    // -------- MFMA2: xhat^T[d][b] from LDS codebook -------------------------
    f32x4 acc2[4];
#pragma unroll
    for (int rf2 = 0; rf2 < 4; ++rf2) acc2[rf2] = (f32x4){0.f, 0.f, 0.f, 0.f};
#pragma unroll
    for (int rf2 = 0; rf2 < 4; ++rf2) {
#pragma unroll
      for (int kf = 0; kf < 8; ++kf) {
        const char* p = (kf & 1) ? (B_o + (kf & ~1) * 64) : (B_e + kf * 64);
        s16x8 A = *(const s16x8*)(p + rf2 * 8192);
        acc2[rf2] = __builtin_amdgcn_mfma_f32_16x16x32_bf16(A, Bp[kf], acc2[rf2], 0, 0, 0);
      }
    }

    // -------- store x_hat via swizzled staging (2 halves of 32 d) -----------
#pragma unroll
    for (int h = 0; h < 2; ++h) {
      LGKM0();  // WAR guard
      *(f32x4*)Sw0 = acc2[2 * h];
      *(f32x4*)Sw1 = acc2[2 * h + 1];
      LGKM0();  // RAW
#pragma unroll
      for (int p = 0; p < 2; ++p) {
        f32x4 v = *(const f32x4*)(Srd + p * 1024);
        int grow = rowblk + t * rowstep + p * 8 + rrow;
        __builtin_nontemporal_store(
            v, (f32x4*)(xhat + (size_t)grow * xstr + m * DD + h * 32 + slot * 4));
      }
    }

    xv[0] = xn[0]; xv[1] = xn[1]; xv[2] = xn[2]; xv[3] = xn[3];
  }
}

extern "C" void kernel_launch(void* const* d_in, const int* in_sizes, int n_in,
                              void* d_out, int out_size, void* d_ws, size_t ws_size,
                              hipStream_t stream) {
  const float* x = (const float*)d_in[0];
  const float* C = (const float*)d_in[1];
  const int B = in_sizes[0] / (MM * DD);   // 65536

  float* xhat = (float*)d_out;
  float* codes = (float*)d_out + (size_t)B * MM * DD;

  u16* Cm = (u16*)d_ws;
  u16* Cmt = Cm + MM * KD * DD;   // 512 KB total in ws

  const int niter = B / (NBG * WAVES * 16);        // 4

  pq_prep<<<(MM * KD * DD + 255) / 256, 256, 0, stream>>>(C, Cm, Cmt);
  pq_main<<<NBG * MM, WAVES * 64, 0, stream>>>(x, Cm, Cmt, xhat, codes, niter);
}